// Round 5
// baseline (269.568 us; speedup 1.0000x reference)
//
#include <hip/hip_runtime.h>

// BeliefPlausibilityFocused: outputs are two broadcast mask tensors.
//   n_sets = 2^(last_dim-1) = 8 (input last dim fixed at 4 by setup_inputs).
//   bel[..., j] = ((j & focal) == focal) ? 1 : 0
//   pl[...,  j] = ((j & focal) >  0)    ? 1 : 0
// Input values are never read — pure store-bandwidth kernel (245.4 MB stores).
// d_out = [bel | pl] contiguous -> treated as ONE flat float4 stream.
//
// v6 vs v5 (~58µs kernel, 4.2 TB/s):
//   Experiment matrix so far: broken-coalescing 2.2 TB/s; grid-stride loop
//   3.2 TB/s; one-shot 1-store/thread 4.2 TB/s; harness fill 6.3 TB/s.
//   nt-vs-plain and 1-vs-2 streams: neutral. Remaining structural gap to
//   the fill: payload per wave. v5 waves s_load focal (~200cy), compute
//   ~15 VALU, issue ONE 1KB store, die — and 59,904 workgroups stress CP
//   dispatch (~1 WG/cy ~= 25µs of ramp).
//   Fix: 4 stores per thread at BLOCK-stride spacing (s*256 float4s), so
//   each store instruction is still a contiguous 1KB wave-segment (the
//   v2 mistake — thread-contiguous spacing — is NOT repeated). Straight-
//   line code, no loop. Blocks 59,904 -> 14,976; 4KB payload/wave.

typedef float f32x4 __attribute__((ext_vector_type(4)));

#define F4_PER_BLOCK 1024LL  // 4 stores * 256 threads

__global__ void __launch_bounds__(256)
BeliefPlausibilityFocused_35656818492191_kernel(const int* __restrict__ focal_p,
                                                float* __restrict__ out,
                                                long long n4_per_out,
                                                long long n4_total) {
    const int focal = *focal_p;  // uniform scalar load, broadcast

    // Channel patterns repeat every 8 floats = two float4s (A=ch0..3, B=ch4..7).
    float b[8], p[8];
#pragma unroll
    for (int j = 0; j < 8; ++j) {
        const int c = j & focal;
        b[j] = (c == focal) ? 1.0f : 0.0f;
        p[j] = (c > 0) ? 1.0f : 0.0f;
    }
    const f32x4 bA = {b[0], b[1], b[2], b[3]};
    const f32x4 bB = {b[4], b[5], b[6], b[7]};
    const f32x4 pA = {p[0], p[1], p[2], p[3]};
    const f32x4 pB = {p[4], p[5], p[6], p[7]};

    // All four store indices share parity (strides are even): t&1 picks A/B.
    const bool odd = (threadIdx.x & 1);
    const f32x4 vb = odd ? bB : bA;
    const f32x4 vp = odd ? pB : pA;

    const long long base = (long long)blockIdx.x * F4_PER_BLOCK + threadIdx.x;
    f32x4* __restrict__ o = (f32x4*)out;

#pragma unroll
    for (int s = 0; s < 4; ++s) {  // fully unrolled: straight-line, no branch
        const long long i = base + (long long)s * 256;
        if (i < n4_total) {  // always true for this shape (exact division)
            o[i] = (i >= n4_per_out) ? vp : vb;
        }
    }
}

extern "C" void kernel_launch(void* const* d_in, const int* in_sizes, int n_in,
                              void* d_out, int out_size, void* d_ws, size_t ws_size,
                              hipStream_t stream) {
    // d_in[0] = inputs (fp32, values unused); d_in[1] = focal (int scalar).
    const int* focal = (const int*)d_in[1];
    float* out = (float*)d_out;

    const long long per_out = (long long)out_size / 2;  // floats per output tensor
    const long long n4_per_out = per_out / 4;           // float4s per output tensor
    const long long n4_total = (long long)out_size / 4; // float4s across both

    const int threads = 256;
    const int blocks = (int)((n4_total + F4_PER_BLOCK - 1) / F4_PER_BLOCK);  // 14,976

    BeliefPlausibilityFocused_35656818492191_kernel<<<blocks, threads, 0, stream>>>(
        focal, out, n4_per_out, n4_total);
}

// Round 6
// 262.040 us; speedup vs baseline: 1.0287x; 1.0287x over previous
//
#include <hip/hip_runtime.h>

// BeliefPlausibilityFocused: outputs are two broadcast mask tensors.
//   n_sets = 2^(last_dim-1) = 8 (input last dim fixed at 4 by setup_inputs).
//   bel[..., j] = ((j & focal) == focal) ? 1 : 0
//   pl[...,  j] = ((j & focal) >  0)    ? 1 : 0
// Input values are never read — pure store-bandwidth kernel (245.4 MB stores).
// d_out = [bel (out_size/2 floats) | pl (out_size/2 floats)] — CONTIGUOUS,
// treated as ONE flat float4 stream.
//
// v7 = v5 REVERT (best measured: 260.8 µs total, kernel ~58 µs @ 4.2 TB/s).
// Final experiment matrix over this session:
//   broken coalescing (thread-contig 64B)  -> 2.2 TB/s (WRITE_SIZE 2.56x)
//   grid-stride loop (2048 blk, nt/plain)  -> ~3.3 TB/s (nt vs plain neutral)
//   one-shot 1 store/thread (this kernel)  -> ~4.2 TB/s  <- BEST
//   one-shot 4 block-strided stores/thread -> ~3.6 TB/s
//   harness fill (981 MB, same chip)       ->  6.3 TB/s
// Mechanisms for the residual gap each falsified: coalescing maximal
// (16B/lane contiguous -> 1KB/instruction), zero write amplification,
// ~8x TLP headroom over wave lifetime, CP dispatch rate exonerated (fill
// launches 4x more WGs at full BW; 4x fewer dispatches didn't help).
// Residual is size-dependent (245 MB vs 981 MB stream), not controllable
// from kernel source -> practical roofline.

typedef float f32x4 __attribute__((ext_vector_type(4)));

__global__ void __launch_bounds__(256)
BeliefPlausibilityFocused_35656818492191_kernel(const int* __restrict__ focal_p,
                                                float* __restrict__ out,
                                                long long n4_per_out,
                                                long long n4_total) {
    const long long i = (long long)blockIdx.x * blockDim.x + threadIdx.x;
    if (i >= n4_total) return;

    const int focal = *focal_p;  // uniform scalar load, broadcast

    // Channel patterns repeat every 8 floats = two float4s (A=ch0..3, B=ch4..7).
    float b[8], p[8];
#pragma unroll
    for (int j = 0; j < 8; ++j) {
        const int c = j & focal;
        b[j] = (c == focal) ? 1.0f : 0.0f;
        p[j] = (c > 0) ? 1.0f : 0.0f;
    }
    const f32x4 bA = {b[0], b[1], b[2], b[3]};
    const f32x4 bB = {b[4], b[5], b[6], b[7]};
    const f32x4 pA = {p[0], p[1], p[2], p[3]};
    const f32x4 pB = {p[4], p[5], p[6], p[7]};

    const bool is_pl = (i >= n4_per_out);
    const bool odd = (i & 1);
    const f32x4 v = is_pl ? (odd ? pB : pA) : (odd ? bB : bA);

    ((f32x4*)out)[i] = v;  // one coalesced 16B store per thread (1KB/wave-instr)
}

extern "C" void kernel_launch(void* const* d_in, const int* in_sizes, int n_in,
                              void* d_out, int out_size, void* d_ws, size_t ws_size,
                              hipStream_t stream) {
    // d_in[0] = inputs (fp32, values unused); d_in[1] = focal (int scalar).
    const int* focal = (const int*)d_in[1];
    float* out = (float*)d_out;

    const long long per_out = (long long)out_size / 2;  // floats per output tensor
    const long long n4_per_out = per_out / 4;           // float4s per output tensor
    const long long n4_total = (long long)out_size / 4; // float4s across both

    const int threads = 256;
    const int blocks = (int)((n4_total + threads - 1) / threads);  // 59,904

    BeliefPlausibilityFocused_35656818492191_kernel<<<blocks, threads, 0, stream>>>(
        focal, out, n4_per_out, n4_total);
}